// Round 4
// baseline (587.229 us; speedup 1.0000x reference)
//
#include <hip/hip_runtime.h>
#include <hip/hip_bf16.h>
#include <math.h>

// Problem constants (B=4,S=1024,D=1024,H=4096,E=8,K=2)
#define TOKENS 4096
#define DD 1024
#define HH 4096
#define NE 8
#define PAIRS 8192     // TOKENS * K
#define ROWCAP 8448    // PAIRS + 256 slack for tile overread
#define T1CAP 40       // max sum ceil(n_e/256) = 39
#define T2CAP 72       // max sum ceil(n_e/128) = 71
#define G1_NT 16       // gemm1 K-tiles (1024/64)
#define G2_NT 32       // gemm2 K-tiles per K-half (2048/64)

typedef __bf16 bf16x8 __attribute__((ext_vector_type(8)));
typedef float f32x4 __attribute__((ext_vector_type(4)));

__device__ __forceinline__ unsigned short f2bf(float f) {
  union { float f; unsigned int u; } c; c.f = f;
  unsigned int x = c.u;
  return (unsigned short)((x + 0x7fffu + ((x >> 16) & 1u)) >> 16);  // RNE
}

__device__ __forceinline__ void lds16(void* l, const void* g) {
  __builtin_amdgcn_global_load_lds((const __attribute__((address_space(1))) void*)g,
                                   (__attribute__((address_space(3))) void*)l, 16, 0, 0);
}

// ---------------- init ----------------
__global__ void init_kernel(int* counts) {
  if (threadIdx.x < NE) counts[threadIdx.x] = 0;
}

// ---------------- transpose+convert: [E][R][C] f32 -> [E][C][R] bf16 ----------------
__global__ __launch_bounds__(256) void transpose_kernel(const float* __restrict__ in,
                                                        unsigned short* __restrict__ out,
                                                        int R, int C) {
  int ntr = R >> 6, ntc = C >> 6;
  int per_e = ntr * ntc;
  int b = blockIdx.x;
  int e = b / per_e;
  int rem = b - e * per_e;
  int tr = rem / ntc, tc = rem - (rem / ntc) * ntc;
  const float* ie = in + (size_t)e * R * C;
  unsigned short* oe = out + (size_t)e * R * C;

  __shared__ float t[64][68];
  int tid = threadIdx.x;
  int lr = tid >> 2;
  int c4 = (tid & 3) << 4;
  const float* src = ie + (size_t)(tr * 64 + lr) * C + tc * 64 + c4;
  float4 v0 = *(const float4*)(src);
  float4 v1 = *(const float4*)(src + 4);
  float4 v2 = *(const float4*)(src + 8);
  float4 v3 = *(const float4*)(src + 12);
  *(float4*)&t[lr][c4] = v0;
  *(float4*)&t[lr][c4 + 4] = v1;
  *(float4*)&t[lr][c4 + 8] = v2;
  *(float4*)&t[lr][c4 + 12] = v3;
  __syncthreads();

  int oc = tid >> 2;
  int r0 = (tid & 3) << 4;
  unsigned int pk[8];
#pragma unroll
  for (int i = 0; i < 8; i++) {
    unsigned int lo = f2bf(t[r0 + 2 * i][oc]);
    unsigned int hi = f2bf(t[r0 + 2 * i + 1][oc]);
    pk[i] = lo | (hi << 16);
  }
  unsigned short* dst = oe + (size_t)(tc * 64 + oc) * R + tr * 64 + r0;
  *(uint4*)(dst) = make_uint4(pk[0], pk[1], pk[2], pk[3]);
  *(uint4*)(dst + 8) = make_uint4(pk[4], pk[5], pk[6], pk[7]);
}

// ---------------- gate ----------------
__global__ __launch_bounds__(256) void gate_kernel(const float* __restrict__ x,
    const float* __restrict__ Wg, const float* __restrict__ bg,
    int* __restrict__ counts, int* __restrict__ tok_e, int* __restrict__ tok_slot,
    float* __restrict__ tok_w) {
  int t = blockIdx.x, tid = threadIdx.x;
  const float* xr = x + (size_t)t * DD;
  float p[8] = {0, 0, 0, 0, 0, 0, 0, 0};
  for (int d = tid; d < DD; d += 256) {
    float xv = xr[d];
    const float4* wrow = (const float4*)(Wg + (size_t)d * NE);
    float4 w0 = wrow[0], w1 = wrow[1];
    p[0] += xv * w0.x; p[1] += xv * w0.y; p[2] += xv * w0.z; p[3] += xv * w0.w;
    p[4] += xv * w1.x; p[5] += xv * w1.y; p[6] += xv * w1.z; p[7] += xv * w1.w;
  }
#pragma unroll
  for (int e = 0; e < 8; e++) {
    p[e] += __shfl_down(p[e], 32);
    p[e] += __shfl_down(p[e], 16);
    p[e] += __shfl_down(p[e], 8);
    p[e] += __shfl_down(p[e], 4);
    p[e] += __shfl_down(p[e], 2);
    p[e] += __shfl_down(p[e], 1);
  }
  __shared__ float red[4][8];
  if ((tid & 63) == 0) {
#pragma unroll
    for (int e = 0; e < 8; e++) red[tid >> 6][e] = p[e];
  }
  __syncthreads();
  if (tid == 0) {
    float l[8];
#pragma unroll
    for (int e = 0; e < 8; e++) l[e] = red[0][e] + red[1][e] + red[2][e] + red[3][e] + bg[e];
    int e0 = 0; float l0 = l[0];
    for (int e = 1; e < 8; e++) if (l[e] > l0) { e0 = e; l0 = l[e]; }
    int e1 = -1; float l1 = -3.4e38f;
    for (int e = 0; e < 8; e++) if (e != e0 && l[e] > l1) { e1 = e; l1 = l[e]; }
    float w0 = 1.f / (1.f + __expf(l1 - l0));
    float w1 = 1.f - w0;
    int s0 = atomicAdd(&counts[e0], 1);
    int s1 = atomicAdd(&counts[e1], 1);
    tok_e[2 * t] = e0;     tok_slot[2 * t] = s0;     tok_w[2 * t] = w0;
    tok_e[2 * t + 1] = e1; tok_slot[2 * t + 1] = s1; tok_w[2 * t + 1] = w1;
  }
}

// ---------------- scan: expert offsets + two tile maps (256-row, 128-row) ----------------
__global__ void scan_kernel(const int* __restrict__ counts, int* __restrict__ offsets,
                            int* __restrict__ tm1_e, int* __restrict__ tm1_row0,
                            int* __restrict__ tm1_nrow, int* __restrict__ ntp1,
                            int* __restrict__ tm2_e, int* __restrict__ tm2_row0,
                            int* __restrict__ tm2_nrow, int* __restrict__ ntp2) {
  if (threadIdx.x != 0 || blockIdx.x != 0) return;
  int c[NE];
#pragma unroll
  for (int e = 0; e < NE; e++) c[e] = counts[e];
  int off = 0, n1 = 0, n2 = 0;
  for (int e = 0; e < NE; e++) {
    offsets[e] = off;
    for (int r = 0; r < c[e]; r += 256) {
      tm1_e[n1] = e; tm1_row0[n1] = off + r;
      tm1_nrow[n1] = (c[e] - r < 256) ? (c[e] - r) : 256;
      n1++;
    }
    for (int r = 0; r < c[e]; r += 128) {
      tm2_e[n2] = e; tm2_row0[n2] = off + r;
      tm2_nrow[n2] = (c[e] - r < 128) ? (c[e] - r) : 128;
      n2++;
    }
    off += c[e];
  }
  *ntp1 = n1;
  *ntp2 = n2;
}

// ---------------- gather ----------------
__global__ __launch_bounds__(64) void gather_kernel(const float* __restrict__ x,
    const int* __restrict__ tok_e, const int* __restrict__ tok_slot,
    const float* __restrict__ tok_w, const int* __restrict__ offsets,
    unsigned short* __restrict__ Xe, int* __restrict__ pair_row, float* __restrict__ rw) {
  int pp = blockIdx.x, tid = threadIdx.x;
  int e = tok_e[pp];
  int row = offsets[e] + tok_slot[pp];
  int t = pp >> 1;
  const float* src = x + (size_t)t * DD + tid * 16;
  float4 v0 = *(const float4*)(src);
  float4 v1 = *(const float4*)(src + 4);
  float4 v2 = *(const float4*)(src + 8);
  float4 v3 = *(const float4*)(src + 12);
  unsigned int pk[8];
  pk[0] = f2bf(v0.x) | ((unsigned int)f2bf(v0.y) << 16);
  pk[1] = f2bf(v0.z) | ((unsigned int)f2bf(v0.w) << 16);
  pk[2] = f2bf(v1.x) | ((unsigned int)f2bf(v1.y) << 16);
  pk[3] = f2bf(v1.z) | ((unsigned int)f2bf(v1.w) << 16);
  pk[4] = f2bf(v2.x) | ((unsigned int)f2bf(v2.y) << 16);
  pk[5] = f2bf(v2.z) | ((unsigned int)f2bf(v2.w) << 16);
  pk[6] = f2bf(v3.x) | ((unsigned int)f2bf(v3.y) << 16);
  pk[7] = f2bf(v3.z) | ((unsigned int)f2bf(v3.w) << 16);
  unsigned short* dst = Xe + (size_t)row * DD + tid * 16;
  *(uint4*)(dst) = make_uint4(pk[0], pk[1], pk[2], pk[3]);
  *(uint4*)(dst + 8) = make_uint4(pk[4], pk[5], pk[6], pk[7]);
  if (tid == 0) { pair_row[pp] = row; rw[row] = tok_w[pp]; }
}

// ================= GEMM1: m201-discipline 4-phase schedule =================
// BM=256, BN=128 dual (Wa,W1), BK=64, 512 thr (8 waves 2Mx4N), 128KB LDS dbuf.
// Phase: {ds_reads; stage; barrier; lgkm(0); sched_barrier; setprio1; 16 MFMA; setprio0; barrier}
// vmcnt(6) once per K-tile (phase 4).
__global__ __launch_bounds__(512, 2) void gemm1_kernel(
    const unsigned short* __restrict__ Xe,
    const unsigned short* __restrict__ WaT,   // [E][H][D] bf16
    const unsigned short* __restrict__ W1T,
    const float* __restrict__ ba, const float* __restrict__ b1,
    unsigned short* __restrict__ h,
    const int* __restrict__ tm_e, const int* __restrict__ tm_row0,
    const int* __restrict__ tm_nrow, const int* __restrict__ ntp) {
  __shared__ unsigned short sm[8][8192];  // [buf*4+slot]; slot 0=A0,1=A1,2=Wa,3=W1

  int work = blockIdx.x;
  int tile = work >> 5;
  if (tile >= *ntp) return;
  int n0 = (work & 31) << 7;
  int e = tm_e[tile], row0 = tm_row0[tile], nrow = tm_nrow[tile];

  int tid = threadIdx.x;
  int lane = tid & 63, wid = tid >> 6;
  int wm = wid >> 2, wn = wid & 3;     // 2M x 4N
  int fr = lane & 15, kc = lane >> 4;

  const unsigned short* gA  = Xe + (size_t)row0 * DD;
  const unsigned short* gA1 = gA + (size_t)128 * DD;
  const unsigned short* gBa = WaT + ((size_t)e << 22) + (size_t)n0 * DD;
  const unsigned short* gBu = W1T + ((size_t)e << 22) + (size_t)n0 * DD;

  int srow = tid >> 3;
  int sx0 = (((tid & 7) ^ (srow & 7)) << 3);   // pre-swizzled source chunk

  auto stg = [&](int tt, int slot, const unsigned short* gsrc) {
    int c = tt < G1_NT ? tt : G1_NT - 1;
    unsigned short* L = &sm[((tt & 1) << 2) | slot][0];
    const unsigned short* s = gsrc + (size_t)srow * DD + (c << 6) + sx0;
    lds16(L + (size_t)tid * 8, s);
    lds16(L + (size_t)(tid + 512) * 8, s + (size_t)64 * DD);
  };
  auto fragp = [&](int buf, int slot, int r, int ks) {
    return (const bf16x8*)(&sm[(buf << 2) | slot][0] + r * 64 +
                           ((((ks << 2) | kc) ^ (r & 7)) << 3));
  };

  f32x4 accA[8][2], accU[8][2];
  f32x4 z = {0.f, 0.f, 0.f, 0.f};
#pragma unroll
  for (int m = 0; m < 8; m++)
#pragma unroll
    for (int n = 0; n < 2; n++) { accA[m][n] = z; accU[m][n] = z; }

  // prologue: T0.{Wa,W1,A0,A1}, T1.{Wa,W1,A0}; certify T0 (6 newest = T1's)
  stg(0, 2, gBa); stg(0, 3, gBu); stg(0, 0, gA); stg(0, 1, gA1);
  stg(1, 2, gBa); stg(1, 3, gBu); stg(1, 0, gA);
  asm volatile("s_waitcnt vmcnt(6)" ::: "memory");
  __builtin_amdgcn_s_barrier();

  for (int T = 0; T < G1_NT; ++T) {
    int buf = T & 1;
    bf16x8 a[4][2], bA[2][2], bU[2][2];
    // ---- P1: read a(mh0)+bA; stage (T+1).A1 (other buf) ----
#pragma unroll
    for (int m = 0; m < 4; m++)
#pragma unroll
      for (int ks = 0; ks < 2; ks++) {
        int R = wm * 128 + m * 16 + fr;
        a[m][ks] = *fragp(buf, R >> 7, R & 127, ks);
      }
#pragma unroll
    for (int n = 0; n < 2; n++)
#pragma unroll
      for (int ks = 0; ks < 2; ks++)
        bA[n][ks] = *fragp(buf, 2, wn * 32 + n * 16 + fr, ks);
    stg(T + 1, 1, gA1);
    __builtin_amdgcn_s_barrier();
    asm volatile("s_waitcnt lgkmcnt(0)" ::: "memory");
    __builtin_amdgcn_sched_barrier(0);
    __builtin_amdgcn_s_setprio(1);
#pragma unroll
    for (int ks = 0; ks < 2; ks++)
#pragma unroll
      for (int m = 0; m < 4; m++)
#pragma unroll
        for (int n = 0; n < 2; n++)
          accA[m][n] = __builtin_amdgcn_mfma_f32_16x16x32_bf16(a[m][ks], bA[n][ks], accA[m][n], 0, 0, 0);
    __builtin_amdgcn_s_setprio(0);
    __builtin_amdgcn_s_barrier();
    // ---- P2: read bU; stage (T+2).Wa (cur buf slot2; readers retired at P1 bar2) ----
#pragma unroll
    for (int n = 0; n < 2; n++)
#pragma unroll
      for (int ks = 0; ks < 2; ks++)
        bU[n][ks] = *fragp(buf, 3, wn * 32 + n * 16 + fr, ks);
    stg(T + 2, 2, gBa);
    __builtin_amdgcn_s_barrier();
    asm volatile("s_waitcnt lgkmcnt(0)" ::: "memory");
    __builtin_amdgcn_sched_barrier(0);
    __builtin_amdgcn_s_setprio(1);
#pragma unroll
    for (int ks = 0; ks < 2; ks++)
#pragma unroll
      for (int m = 0; m < 4; m++)
#pragma unroll
        for (int n = 0; n < 2; n++)
          accU[m][n] = __builtin_amdgcn_mfma_f32_16x16x32_bf16(a[m][ks], bU[n][ks], accU[m][n], 0, 0, 0);
    __builtin_amdgcn_s_setprio(0);
    __builtin_amdgcn_s_barrier();
    // ---- P3: read a(mh1); stage (T+2).W1 ----
#pragma unroll
    for (int m = 0; m < 4; m++)
#pragma unroll
      for (int ks = 0; ks < 2; ks++) {
        int R = wm * 128 + 64 + m * 16 + fr;
        a[m][ks] = *fragp(buf, R >> 7, R & 127, ks);
      }
    stg(T + 2, 3, gBu);
    __builtin_amdgcn_s_barrier();
    asm volatile("s_waitcnt lgkmcnt(0)" ::: "memory");
    __builtin_amdgcn_sched_barrier(0);
    __builtin_amdgcn_s_setprio(1);
#pragma unroll
    for (int ks = 0; ks < 2; ks++)
#pragma unroll
      for (int m = 0; m < 4; m++)
#pragma unroll
        for (int n = 0; n < 2; n++)
          accA[4 + m][n] = __builtin_amdgcn_mfma_f32_16x16x32_bf16(a[m][ks], bA[n][ks], accA[4 + m][n], 0, 0, 0);
    __builtin_amdgcn_s_setprio(0);
    __builtin_amdgcn_s_barrier();
    // ---- P4: stage (T+2).A0; MFMA(mh1,U); vmcnt(6) certifies T+1 ----
    stg(T + 2, 0, gA);
    __builtin_amdgcn_s_barrier();
    __builtin_amdgcn_sched_barrier(0);
    __builtin_amdgcn_s_setprio(1);
#pragma unroll
    for (int ks = 0; ks < 2; ks++)
#pragma unroll
      for (int m = 0; m < 4; m++)
#pragma unroll
        for (int n = 0; n < 2; n++)
          accU[4 + m][n] = __builtin_amdgcn_mfma_f32_16x16x32_bf16(a[m][ks], bU[n][ks], accU[4 + m][n], 0, 0, 0);
    __builtin_amdgcn_s_setprio(0);
    asm volatile("s_waitcnt vmcnt(6)" ::: "memory");
    __builtin_amdgcn_s_barrier();
  }

  // epilogue: SwiGLU -> bf16 h
  int lr4 = kc * 4;
#pragma unroll
  for (int n = 0; n < 2; n++) {
    int col = n0 + wn * 32 + n * 16 + fr;
    float bav = ba[e * HH + col];
    float buv = b1[e * HH + col];
#pragma unroll
    for (int m = 0; m < 8; m++) {
#pragma unroll
      for (int j = 0; j < 4; j++) {
        int r = wm * 128 + m * 16 + lr4 + j;
        if (r < nrow) {
          float av = accA[m][n][j] + bav;
          float uv = accU[m][n][j] + buv;
          float s = __builtin_amdgcn_rcpf(1.f + __expf(-av));
          h[(size_t)(row0 + r) * HH + col] = f2bf(av * s * uv);
        }
      }
    }
  }
}

// ================= GEMM2: m201-discipline 2-phase schedule, K-split=2 =================
// BM=128, BN=256, BK=64, 512 thr (8 waves 2Mx4N, per-wave 64x64).
// A dbuf (2x16KB) + B triple-buffer (3x32KB) = 128KB. vmcnt(6)/iter.
__global__ __launch_bounds__(512, 2) void gemm2_kernel(
    const unsigned short* __restrict__ hb,
    const unsigned short* __restrict__ W2T,   // [E][D][H] bf16
    const float* __restrict__ b2, const float* __restrict__ rw,
    float* __restrict__ contribA, float* __restrict__ contribB,
    const int* __restrict__ tm_e, const int* __restrict__ tm_row0,
    const int* __restrict__ tm_nrow, const int* __restrict__ ntp) {
  __shared__ unsigned short smA[2][8192];    // [parity][128*64]
  __shared__ unsigned short smB[3][16384];   // [t%3][256*64]

  int work = blockIdx.x;
  int tile = work >> 3;
  if (tile >= *ntp) return;
  int rem = work & 7;
  int n0 = (rem >> 1) << 8;   // 0,256,512,768
  int kh = rem & 1;
  int e = tm_e[tile], row0 = tm_row0[tile], nrow = tm_nrow[tile];

  int tid = threadIdx.x;
  int lane = tid & 63, wid = tid >> 6;
  int wm = wid >> 2, wn = wid & 3;     // 2M x 4N
  int fr = lane & 15, kc = lane >> 4;

  const unsigned short* gA = hb + (size_t)row0 * HH + kh * 2048;
  const unsigned short* gB = W2T + ((size_t)e << 22) + (size_t)n0 * HH + kh * 2048;

  int srow = tid >> 3;
  int sx0 = (((tid & 7) ^ (srow & 7)) << 3);

  auto stgA = [&](int tt) {   // 128x64, 2 loads
    int c = tt < G2_NT ? tt : G2_NT - 1;
    unsigned short* L = &smA[tt & 1][0];
    const unsigned short* s = gA + (size_t)srow * HH + (c << 6) + sx0;
    lds16(L + (size_t)tid * 8, s);
    lds16(L + (size_t)(tid + 512) * 8, s + (size_t)64 * HH);
  };
  auto stgB = [&](int tt) {   // 256x64, 4 loads
    int c = tt < G2_NT ? tt : G2_NT - 1;
    unsigned short* L = &smB[tt % 3][0];
    const unsigned short* s = gB + (size_t)srow * HH + (c << 6) + sx0;
    lds16(L + (size_t)tid * 8, s);
    lds16(L + (size_t)(tid + 512) * 8, s + (size_t)64 * HH);
    lds16(L + (size_t)(tid + 1024) * 8, s + (size_t)128 * HH);
    lds16(L + (size_t)(tid + 1536) * 8, s + (size_t)192 * HH);
  };
  auto fragA = [&](int par, int r, int ks) {
    return (const bf16x8*)(&smA[par][0] + r * 64 + ((((ks << 2) | kc) ^ (r & 7)) << 3));
  };
  auto fragB = [&](int slot, int r, int ks) {
    return (const bf16x8*)(&smB[slot][0] + r * 64 + ((((ks << 2) | kc) ^ (r & 7)) << 3));
  };

  f32x4 acc[4][4];
  f32x4 z = {0.f, 0.f, 0.f, 0.f};
#pragma unroll
  for (int m = 0; m < 4; m++)
#pragma unroll
    for (int n = 0; n < 4; n++) acc[m][n] = z;

  // prologue: B0,A0,B1,A1 (12 loads); certify T0 (newest 6 = B1(4)+A1(2))
  stgB(0); stgA(0); stgB(1); stgA(1);
  asm volatile("s_waitcnt vmcnt(6)" ::: "memory");
  __builtin_amdgcn_s_barrier();

  for (int T = 0; T < G2_NT; ++T) {
    int par = T & 1, slB = T % 3;
    bf16x8 a[4][2], b[4][2];
    // ---- P1: read all a + b(n0,n1); stage B(T+2) (slot (T+2)%3, idle since T-1) ----
#pragma unroll
    for (int m = 0; m < 4; m++)
#pragma unroll
      for (int ks = 0; ks < 2; ks++)
        a[m][ks] = *fragA(par, wm * 64 + m * 16 + fr, ks);
#pragma unroll
    for (int n = 0; n < 2; n++)
#pragma unroll
      for (int ks = 0; ks < 2; ks++)
        b[n][ks] = *fragB(slB, wn * 64 + n * 16 + fr, ks);
    stgB(T + 2);
    __builtin_amdgcn_s_barrier();
    asm volatile("s_waitcnt lgkmcnt(0)" ::: "memory");
    __builtin_amdgcn_sched_barrier(0);
    __builtin_amdgcn_s_setprio(1);
#pragma unroll
    for (int ks = 0; ks < 2; ks++)
#pragma unroll
      for (int m = 0; m < 4; m++)
#pragma unroll
        for (int n = 0; n < 2; n++)
          acc[m][n] = __builtin_amdgcn_mfma_f32_16x16x32_bf16(a[m][ks], b[n][ks], acc[m][n], 0, 0, 0);
    __builtin_amdgcn_s_setprio(0);
    __builtin_amdgcn_s_barrier();
    // ---- P2: read b(n2,n3); stage A(T+2) (cur parity; a-readers retired at P1 bar2) ----
#pragma unroll
    for (int n = 2; n < 4; n++)
#pragma unroll
      for (int ks = 0; ks < 2; ks++)
        b[n][ks] = *fragB(slB, wn * 64 + n * 16 + fr, ks);
    stgA(T + 2);
    __builtin_amdgcn_s_barrier();
    asm volatile("s_waitcnt lgkmcnt(0)" ::: "memory");
    __builtin_amdgcn_sched_barrier(0);
    __builtin_amdgcn_s_setprio(1);
#pragma unroll
    for (int ks = 0; ks < 2; ks++)
#pragma unroll
      for (int m = 0; m < 4; m++)
#pragma unroll
        for (int n = 2; n < 4; n++)
          acc[m][n] = __builtin_amdgcn_mfma_f32_16x16x32_bf16(a[m][ks], b[n][ks], acc[m][n], 0, 0, 0);
    __builtin_amdgcn_s_setprio(0);
    asm volatile("s_waitcnt vmcnt(6)" ::: "memory");
    __builtin_amdgcn_s_barrier();
  }

  float b2v[4];
#pragma unroll
  for (int n = 0; n < 4; n++)
    b2v[n] = (kh == 0) ? b2[e * DD + n0 + wn * 64 + n * 16 + fr] : 0.f;
  float* cbuf = kh ? contribB : contribA;
  int lr4 = kc * 4;
#pragma unroll
  for (int m = 0; m < 4; m++) {
#pragma unroll
    for (int j = 0; j < 4; j++) {
      int r = wm * 64 + m * 16 + lr4 + j;
      if (r < nrow) {
        float wv = rw[row0 + r];
        float* dst = cbuf + (size_t)(row0 + r) * DD + n0 + wn * 64 + fr;
#pragma unroll
        for (int n = 0; n < 4; n++)
          dst[n * 16] = wv * (acc[m][n][j] + b2v[n]);
      }
    }
  }
}

// ---------------- combine ----------------
__global__ __launch_bounds__(256) void combine_kernel(const float* __restrict__ cA,
    const float* __restrict__ cB, const int* __restrict__ pair_row,
    float* __restrict__ out) {
  int t = blockIdx.x, tid = threadIdx.x;
  int r0 = pair_row[2 * t], r1 = pair_row[2 * t + 1];
  const float4* a0 = (const float4*)(cA + (size_t)r0 * DD);
  const float4* b0 = (const float4*)(cB + (size_t)r0 * DD);
  const float4* a1 = (const float4*)(cA + (size_t)r1 * DD);
  const float4* b1 = (const float4*)(cB + (size_t)r1 * DD);
  float4* o = (float4*)(out + (size_t)t * DD);
  float4 x0 = a0[tid], y0 = b0[tid], x1 = a1[tid], y1 = b1[tid];
  o[tid] = make_float4((x0.x + y0.x) + (x1.x + y1.x),
                       (x0.y + y0.y) + (x1.y + y1.y),
                       (x0.z + y0.z) + (x1.z + y1.z),
                       (x0.w + y0.w) + (x1.w + y1.w));
}

extern "C" void kernel_launch(void* const* d_in, const int* in_sizes, int n_in,
                              void* d_out, int out_size, void* d_ws, size_t ws_size,
                              hipStream_t stream) {
  const float* x  = (const float*)d_in[0];
  const float* Wg = (const float*)d_in[1];
  const float* bg = (const float*)d_in[2];
  const float* W1 = (const float*)d_in[3];
  const float* b1 = (const float*)d_in[4];
  const float* Wa = (const float*)d_in[5];
  const float* ba = (const float*)d_in[6];
  const float* W2 = (const float*)d_in[7];
  const float* b2 = (const float*)d_in[8];
  float* out = (float*)d_out;
  (void)in_sizes; (void)n_in; (void)out_size; (void)ws_size;

  char* p = (char*)d_ws;
  auto take = [&](size_t bytes) { char* r = p; p += (bytes + 255) & ~(size_t)255; return r; };
  unsigned short* WaT = (unsigned short*)take((size_t)NE * HH * DD * 2);
  unsigned short* W1T = (unsigned short*)take((size_t)NE * HH * DD * 2);
  unsigned short* W2T = (unsigned short*)take((size_t)NE * DD * HH * 2);
  unsigned short* Xe  = (unsigned short*)take((size_t)ROWCAP * DD * 2);
  unsigned short* hb  = (unsigned short*)take((size_t)ROWCAP * HH * 2);
  float* contribA     = (float*)take((size_t)ROWCAP * DD * 4);
  int* counts   = (int*)take(64);
  int* offsets  = (int*)take(64);
  int* tok_e    = (int*)take(PAIRS * 4);
  int* tok_slot = (int*)take(PAIRS * 4);
  float* tok_w  = (float*)take(PAIRS * 4);
  int* pair_row = (int*)take(PAIRS * 4);
  float* rw     = (float*)take(ROWCAP * 4);
  int* tm1_e    = (int*)take(T1CAP * 4);
  int* tm1_row0 = (int*)take(T1CAP * 4);
  int* tm1_nrow = (int*)take(T1CAP * 4);
  int* ntp1     = (int*)take(64);
  int* tm2_e    = (int*)take(T2CAP * 4);
  int* tm2_row0 = (int*)take(T2CAP * 4);
  int* tm2_nrow = (int*)take(T2CAP * 4);
  int* ntp2     = (int*)take(64);
  // contribB aliases WaT (dead after gemm1; stream-ordered)
  float* contribB = (float*)WaT;

  init_kernel<<<1, 64, 0, stream>>>(counts);
  transpose_kernel<<<NE * 16 * 64, 256, 0, stream>>>(Wa, WaT, DD, HH);
  transpose_kernel<<<NE * 16 * 64, 256, 0, stream>>>(W1, W1T, DD, HH);
  transpose_kernel<<<NE * 64 * 16, 256, 0, stream>>>(W2, W2T, HH, DD);
  gate_kernel<<<TOKENS, 256, 0, stream>>>(x, Wg, bg, counts, tok_e, tok_slot, tok_w);
  scan_kernel<<<1, 64, 0, stream>>>(counts, offsets, tm1_e, tm1_row0, tm1_nrow, ntp1,
                                    tm2_e, tm2_row0, tm2_nrow, ntp2);
  gather_kernel<<<PAIRS, 64, 0, stream>>>(x, tok_e, tok_slot, tok_w, offsets, Xe, pair_row, rw);
  gemm1_kernel<<<T1CAP * 32, 512, 0, stream>>>(Xe, WaT, W1T, ba, b1, hb, tm1_e, tm1_row0, tm1_nrow, ntp1);
  gemm2_kernel<<<T2CAP * 8, 512, 0, stream>>>(hb, W2T, b2, rw, contribA, contribB, tm2_e, tm2_row0, tm2_nrow, ntp2);
  combine_kernel<<<TOKENS, 256, 0, stream>>>(contribA, contribB, pair_row, out);
}